// Round 2
// baseline (69.329 us; speedup 1.0000x reference)
//
#include <hip/hip_runtime.h>
#include <hip/hip_bf16.h>

// SelfAttentionModule: B=4, C=64, CQ=32, HW=4096, fp32 in/out.
// out[c,j] = sum_i y[c,i]*exp2(qs_i.k_j - m_i) + bl[c] + x[c,j]
//   qs = LOG2E*(Wq x + bq), k = Wk x + bk, y = Wl x, m_i = log2(sum_j exp2(qs_i.k_j))
// R17 = R15 (pass2/merge ISPL=8 restored verbatim) + pass1m restructured:
//   block = 64 i x full 4096 j, grid 256. K staged in LDS chunks (256 j = 16KB,
//   double-buffered, counted-vmcnt one-barrier idiom). Each wave holds ALL 4 Q
//   i-tiles in regs and owns a j-quarter of each chunk -> each ds_read feeds
//   4 MFMAs. Kt L2 traffic 256MB -> 64MB.

#define HW 4096
#define BN 4
#define CD 64
#define ISPL 8
#define LOG2E 1.44269504f

typedef short bf16x8 __attribute__((ext_vector_type(8)));
typedef float f32x4 __attribute__((ext_vector_type(4)));

static __device__ inline unsigned bfbits(float f) {
    union { float f; unsigned u; } v{f};
    return (v.u + 0x8000u) >> 16;
}
static __device__ inline float b2f(short s) {
    unsigned u = ((unsigned)(unsigned short)s) << 16;
    float f; __builtin_memcpy(&f, &u, 4); return f;
}
static __device__ inline int cvtpk(float lo, float hi) {
    __hip_bfloat162 h = __float22bfloat162_rn(make_float2(lo, hi));
    int r; __builtin_memcpy(&r, &h, 4); return r;
}
static __device__ inline void gl16(const void* g, void* l) {
    __builtin_amdgcn_global_load_lds(
        (const __attribute__((address_space(1))) unsigned int*)g,
        (__attribute__((address_space(3))) unsigned int*)l, 16, 0, 0);
}

// ws (bytes): Qt[B*HW][32]bf16 @0 (1MB) | Kt @0x100000 (1MB) | Yc[B][64][HW]bf16 @0x200000 (2MB)
//  mrow[B*HW]f32 @0x500000 (64KB) | Opart[8][B][64][HW]bf16 @0x510000 (16.8MB)

// ---------------- proj: q,k,y projections via MFMA (R7 verbatim) ----------------

__global__ __launch_bounds__(256, 4) void k_proj(
    const float* __restrict__ x, const float* __restrict__ Wq, const float* __restrict__ bq,
    const float* __restrict__ Wk, const float* __restrict__ bk, const float* __restrict__ Wl,
    short* __restrict__ Qt, short* __restrict__ Kt, short* __restrict__ Yc)
{
    __shared__ __align__(16) char sm[18944];
    short* WcL   = (short*)sm;            // [128 rows][64] bf16, slot-swizzled (16KB)
    short* xT    = (short*)(sm + 16384);  // [16 px][64 c] bf16, slot-swizzled (2KB)
    float* biasL = (float*)(sm + 18432);  // [128] f32

    int t = threadIdx.x;
    int wv = t >> 6, l = t & 63, g = l >> 4, n = l & 15;

    {   // pack weights into LDS (redundant per block; L2-hot)
        int row = t >> 1, half = t & 1;
        const float* src; float scale = 1.f;
        if (row < 32)      { src = Wq + row * CD; scale = LOG2E; }
        else if (row < 64) { src = Wk + (row - 32) * CD; }
        else               { src = Wl + (row - 64) * CD; }
        int pk[16];
#pragma unroll
        for (int e = 0; e < 16; ++e)
            pk[e] = cvtpk(src[half * 32 + 2 * e] * scale, src[half * 32 + 2 * e + 1] * scale);
#pragma unroll
        for (int q = 0; q < 4; ++q)
            *(int4*)(WcL + row * 64 + ((((half << 2) + q) ^ (row & 7)) << 3)) =
                make_int4(pk[4 * q], pk[4 * q + 1], pk[4 * q + 2], pk[4 * q + 3]);
        if (half == 0)
            biasL[row] = (row < 32) ? LOG2E * bq[row] : (row < 64) ? bk[row - 32] : 0.f;
    }
    int pix0 = blockIdx.x << 4;           // 16 px per block over B*HW
    {
        int c = t >> 2, q = t & 3;
        int b = pix0 >> 12, pxb = pix0 & (HW - 1);
        float4 v = *(const float4*)(x + ((size_t)b << 18) + ((size_t)c << 12) + pxb + q * 4);
        float vv[4] = {v.x, v.y, v.z, v.w};
#pragma unroll
        for (int e = 0; e < 4; ++e) {
            int px = q * 4 + e;
            xT[px * 64 + (((c >> 3) ^ (px & 7)) << 3) + (c & 7)] = (short)bfbits(vv[e]);
        }
    }
    __syncthreads();

    bf16x8 B0 = *(const bf16x8*)(xT + n * 64 + ((g ^ (n & 7)) << 3));
    bf16x8 B1 = *(const bf16x8*)(xT + n * 64 + (((4 + g) ^ (n & 7)) << 3));
    int pg = pix0 + n;
#pragma unroll
    for (int mm = 0; mm < 2; ++mm) {
        int mt = wv * 2 + mm;
        bf16x8 A0 = *(const bf16x8*)(WcL + (mt * 16 + n) * 64 + ((g ^ (n & 7)) << 3));
        bf16x8 A1 = *(const bf16x8*)(WcL + (mt * 16 + n) * 64 + (((4 + g) ^ (n & 7)) << 3));
        f32x4 d = {0.f, 0.f, 0.f, 0.f};
        d = __builtin_amdgcn_mfma_f32_16x16x32_bf16(A0, B0, d, 0, 0, 0);
        d = __builtin_amdgcn_mfma_f32_16x16x32_bf16(A1, B1, d, 0, 0, 0);
        d += *(const f32x4*)(biasL + mt * 16 + g * 4);
        if (mt < 4) {
            short* dst = (mt < 2 ? Qt : Kt) + ((size_t)pg << 5) + ((mt & 1) << 4) + (g << 2);
            *(int2*)dst = make_int2(cvtpk(d[0], d[1]), cvtpk(d[2], d[3]));
        } else {
            int ch2 = (mt - 4) * 16 + g * 4;
            int bb = pg >> 12, ii = pg & (HW - 1);
#pragma unroll
            for (int r = 0; r < 4; ++r)
                Yc[(((size_t)(bb * CD + ch2 + r)) << 12) + ii] = (short)bfbits(d[r]);
        }
    }
}

// ---- pass1m (R17): m_i = -log2(sum_j exp2(e_ij)); 64 i/block, LDS-shared K ----
// Grid 256 = 64 i-tiles x 4 b. Each block streams its batch's whole Kt slice
// (256KB) ONCE through LDS in 16KB chunks (256 j), double-buffered. Each wave
// holds all 4 Q i-tiles in regs and computes a j-quarter of each chunk, so one
// ds_read_b128 feeds 4 MFMAs. Cross-wave j-partials reduced in LDS at the end.

__global__ __launch_bounds__(256, 4) void k_pass1m(
    const short* __restrict__ Qt, const short* __restrict__ Kt, float* __restrict__ mrow)
{
    __shared__ __align__(16) char sm1[33792];
    short* KL  = (short*)sm1;             // 2 x [256 j][32 k] bf16 (2x16KB)
    float* red = (float*)(sm1 + 32768);   // [4 waves][64 i] f32

    int t = threadIdx.x;
    int wv = t >> 6, l = t & 63, g = l >> 4, n = l & 15;
    int ch = blockIdx.x;                  // 256 = 64 i-tiles x 4 b (b low bits)
    int b = ch & 3, i0 = (ch >> 2) << 6;
    size_t bHW = (size_t)b << 12;

    bf16x8 aq[4];                         // all 4 i-tiles of this block's Q
#pragma unroll
    for (int it = 0; it < 4; ++it)
        aq[it] = *(const bf16x8*)(Qt + ((bHW + i0 + it * 16 + n) << 5) + (g << 3));

    const char* ksrc = (const char*)(Kt + (bHW << 5));  // this b's 256KB Kt slice

    f32x4 ls[4];
#pragma unroll
    for (int it = 0; it < 4; ++it) ls[it] = (f32x4){0.f, 0.f, 0.f, 0.f};

    // prologue: stage chunk 0 (each wave copies a contiguous 4KB), full drain
#pragma unroll
    for (int q = 0; q < 4; ++q) {
        int off = (wv * 4 + q) * 1024 + l * 16;
        gl16(ksrc + off, (char*)KL + off);
    }
    asm volatile("s_waitcnt vmcnt(0)" ::: "memory");
    __builtin_amdgcn_s_barrier();
    __builtin_amdgcn_sched_barrier(0);

    const int NCH = 16;                   // 4096 j / 256
    for (int chk = 0; chk < NCH; ++chk) {
        int cur = chk & 1;
        if (chk > 0) {
            __builtin_amdgcn_s_barrier();  // all waves done reading buf[cur^1]
            __builtin_amdgcn_sched_barrier(0);
        }
        if (chk + 1 < NCH) {
#pragma unroll
            for (int q = 0; q < 4; ++q) {
                int off = (wv * 4 + q) * 1024 + l * 16;
                gl16(ksrc + (size_t)(chk + 1) * 16384 + off,
                     (char*)KL + (cur ^ 1) * 16384 + off);
            }
            asm volatile("s_waitcnt vmcnt(4)" ::: "memory");  // this chunk landed
        } else {
            asm volatile("s_waitcnt vmcnt(0)" ::: "memory");
        }
        __builtin_amdgcn_sched_barrier(0);

        const short* kb = (const short*)((char*)KL + cur * 16384);
#pragma unroll
        for (int jj = 0; jj < 4; ++jj) {  // wave's j-quarter: tiles wv*4..wv*4+3
            bf16x8 bkv = *(const bf16x8*)(kb + (((wv * 4 + jj) * 16 + n) << 5) + (g << 3));
#pragma unroll
            for (int it = 0; it < 4; ++it) {
                f32x4 z = {0.f, 0.f, 0.f, 0.f};
                f32x4 s = __builtin_amdgcn_mfma_f32_16x16x32_bf16(aq[it], bkv, z, 0, 0, 0);
                ls[it][0] += exp2f(s[0]); ls[it][1] += exp2f(s[1]);
                ls[it][2] += exp2f(s[2]); ls[it][3] += exp2f(s[3]);
            }
        }
        __builtin_amdgcn_sched_barrier(0);
    }

    // reduce over the 16 j-columns within each MFMA tile (lane bits 0-3)
#pragma unroll
    for (int msk = 1; msk < 16; msk <<= 1)
#pragma unroll
        for (int it = 0; it < 4; ++it) {
            ls[it][0] += __shfl_xor(ls[it][0], msk, 64);
            ls[it][1] += __shfl_xor(ls[it][1], msk, 64);
            ls[it][2] += __shfl_xor(ls[it][2], msk, 64);
            ls[it][3] += __shfl_xor(ls[it][3], msk, 64);
        }
    if (n == 0)
#pragma unroll
        for (int it = 0; it < 4; ++it)
#pragma unroll
            for (int r = 0; r < 4; ++r)
                red[wv * 64 + it * 16 + g * 4 + r] = ls[it][r];
    __syncthreads();
    if (t < 64) {
        float s = red[t] + red[64 + t] + red[128 + t] + red[192 + t];
        mrow[bHW + i0 + t] = -log2f(s);
    }
}

// --- pass2 (R15 verbatim): counted-vmcnt pipeline, ONE barrier per K-step ---

__global__ __launch_bounds__(256, 4) void k_pass2(
    const short* __restrict__ Qt, const short* __restrict__ Kt,
    const short* __restrict__ Yc, const float* __restrict__ mrow,
    short* __restrict__ Opart)
{
    __shared__ __align__(16) char smem[36864];
    short* QtL = (short*)smem;              // 2 x [64 i][32 k]  (8KB)
    short* W2L = (short*)(smem + 8192);     // 2 x [64 c][64 i] swizzled (16KB)
    short* Pb  = (short*)(smem + 24576);    // 4 waves x [32 j][40] pitch-80B (10KB)
    float* MtA = (float*)(smem + 34816);    // full 512-i (-m) slice (2KB)

    int t = threadIdx.x;
    int wv = t >> 6, l = t & 63, g = l >> 4, n = l & 15;
    int ch = blockIdx.x;                    // 1024 = 4 b x 8 isp x 32 jt
    int b = ch >> 8, isp = (ch >> 5) & 7, jt = ch & 31;
    int j0 = jt * 128 + wv * 32;
    size_t bHW = (size_t)b << 12;
    short* Pw = Pb + wv * 1280;

    bf16x8 bk0 = *(const bf16x8*)(Kt + ((bHW + j0 + n) << 5) + (g << 3));
    bf16x8 bk1 = *(const bf16x8*)(Kt + ((bHW + j0 + 16 + n) << 5) + (g << 3));

    f32x4 oacc[2][4];
#pragma unroll
    for (int a = 0; a < 2; ++a)
#pragma unroll
        for (int m = 0; m < 4; ++m) oacc[a][m] = (f32x4){0.f, 0.f, 0.f, 0.f};

    int swz = ((t & 7) ^ ((t >> 3) & 7)) << 4;
    const char* qsrc = (const char*)Qt + ((bHW + (size_t)isp * 512) << 6) + t * 16;
    const char* wsrc = (const char*)Yc + (((size_t)(b * CD + (t >> 3)) << 12) + isp * 512) * 2 + swz;
    char* qd0 = (char*)QtL + t * 16;  char* qd1 = qd0 + 4096;
    char* wd0 = (char*)W2L + t * 16;  char* wd1 = wd0 + 8192;

    // prologue: stage buf0 + the whole -m slice; full drain once.
    gl16(qsrc, qd0);
    gl16(wsrc, wd0);
    gl16(wsrc + (32ull << 13), wd0 + 4096);
    if (t < 128)    // waves 0-1 (wave-uniform branch): 128 x 16B = 2KB of mrow
        gl16((const char*)(mrow + bHW + (size_t)isp * 512) + t * 16, (char*)MtA + t * 16);
    asm volatile("s_waitcnt vmcnt(0)" ::: "memory");
    __builtin_amdgcn_s_barrier();
    __builtin_amdgcn_sched_barrier(0);

    const int NT = 8;                       // 512 i / 64
    for (int st = 0; st < NT; ++st) {
        int cur = st & 1;
        if (st > 0) {
            // single barrier per step: proves all waves finished reading
            // buf[cur^1] (step st-1's compute) before DMA overwrites it below.
            __builtin_amdgcn_s_barrier();
            __builtin_amdgcn_sched_barrier(0);
        }
        if (st + 1 < NT) {
            gl16(qsrc + (size_t)(st + 1) * 4096, cur ? qd0 : qd1);
            gl16(wsrc + (size_t)(st + 1) * 128, cur ? wd0 : wd1);
            gl16(wsrc + (size_t)(st + 1) * 128 + (32ull << 13), (cur ? wd0 : wd1) + 4096);
            // wait for THIS step's 3 loads (issued at st-1); st+1's 3 stay in flight
            asm volatile("s_waitcnt vmcnt(3)" ::: "memory");
        } else {
            asm volatile("s_waitcnt vmcnt(0)" ::: "memory");
        }
        __builtin_amdgcn_sched_barrier(0);  // no ds_read hoists above (rule #18)

        const short* qL = QtL + cur * 2048;
        const char* wL = (const char*)W2L + cur * 8192;
        const float* mL = MtA + st * 64;
#pragma unroll
        for (int ks = 0; ks < 2; ++ks) {
            bf16x8 aq0 = *(const bf16x8*)(qL + (ks * 32 + n) * 32 + g * 8);
            bf16x8 aq1 = *(const bf16x8*)(qL + (ks * 32 + 16 + n) * 32 + g * 8);
            f32x4 cm0 = *(const f32x4*)(mL + ks * 32 + g * 4);
            f32x4 cm1 = *(const f32x4*)(mL + ks * 32 + 16 + g * 4);
            __builtin_amdgcn_s_setprio(1);
            f32x4 s00 = __builtin_amdgcn_mfma_f32_16x16x32_bf16(aq0, bk0, cm0, 0, 0, 0);
            f32x4 s01 = __builtin_amdgcn_mfma_f32_16x16x32_bf16(aq1, bk0, cm1, 0, 0, 0);
            f32x4 s10 = __builtin_amdgcn_mfma_f32_16x16x32_bf16(aq0, bk1, cm0, 0, 0, 0);
            f32x4 s11 = __builtin_amdgcn_mfma_f32_16x16x32_bf16(aq1, bk1, cm1, 0, 0, 0);
            __builtin_amdgcn_s_setprio(0);
            *(int2*)(Pw + n * 40 + 4 * g) =
                make_int2(cvtpk(exp2f(s00[0]), exp2f(s00[1])), cvtpk(exp2f(s00[2]), exp2f(s00[3])));
            *(int2*)(Pw + n * 40 + 16 + 4 * g) =
                make_int2(cvtpk(exp2f(s01[0]), exp2f(s01[1])), cvtpk(exp2f(s01[2]), exp2f(s01[3])));
            *(int2*)(Pw + (16 + n) * 40 + 4 * g) =
                make_int2(cvtpk(exp2f(s10[0]), exp2f(s10[1])), cvtpk(exp2f(s10[2]), exp2f(s10[3])));
            *(int2*)(Pw + (16 + n) * 40 + 16 + 4 * g) =
                make_int2(cvtpk(exp2f(s11[0]), exp2f(s11[1])), cvtpk(exp2f(s11[2]), exp2f(s11[3])));
            bf16x8 pb0 = *(const bf16x8*)(Pw + n * 40 + 8 * g);
            bf16x8 pb1 = *(const bf16x8*)(Pw + (16 + n) * 40 + 8 * g);
            __builtin_amdgcn_s_setprio(1);
#pragma unroll
            for (int mb = 0; mb < 4; ++mb) {
                bf16x8 aw = *(const bf16x8*)(wL + (mb * 16 + n) * 128 + ((((ks << 2) + g) ^ (n & 7)) << 4));
                oacc[0][mb] = __builtin_amdgcn_mfma_f32_16x16x32_bf16(aw, pb0, oacc[0][mb], 0, 0, 0);
                oacc[1][mb] = __builtin_amdgcn_mfma_f32_16x16x32_bf16(aw, pb1, oacc[1][mb], 0, 0, 0);
            }
            __builtin_amdgcn_s_setprio(0);
        }
        __builtin_amdgcn_sched_barrier(0);  // no ds_read sinks past next barrier
    }
    size_t obase = ((((size_t)isp * BN + b) * CD) << 12) + j0 + n;
#pragma unroll
    for (int j2 = 0; j2 < 2; ++j2)
#pragma unroll
        for (int mb = 0; mb < 4; ++mb)
#pragma unroll
            for (int r = 0; r < 4; ++r)
                Opart[obase + (((size_t)(mb * 16 + g * 4 + r)) << 12) + j2 * 16] =
                    (short)bfbits(oacc[j2][mb][r]);
}

// ---------------- merge (R15 verbatim): sum partials + bias + residual ----------------

__global__ __launch_bounds__(256, 4) void k_merge(
    const short* __restrict__ Opart, const float* __restrict__ x,
    const float* __restrict__ bl, float* __restrict__ out)
{
    int t = threadIdx.x;
    int e = (blockIdx.x * 256 + t) * 4;
    int c = (e >> 12) & 63;
    float4 r = *(const float4*)(x + e);
    float bc = bl[c];
    r.x += bc; r.y += bc; r.z += bc; r.w += bc;
#pragma unroll
    for (int p = 0; p < ISPL; ++p) {
        int2 o4 = *(const int2*)(Opart + ((size_t)p << 20) + e);
        r.x += b2f((short)(o4.x & 0xffff));
        r.y += b2f((short)(o4.x >> 16));
        r.z += b2f((short)(o4.y & 0xffff));
        r.w += b2f((short)(o4.y >> 16));
    }
    *(float4*)(out + e) = r;
}

extern "C" void kernel_launch(void* const* d_in, const int* in_sizes, int n_in,
                              void* d_out, int out_size, void* d_ws, size_t ws_size,
                              hipStream_t stream)
{
    (void)in_sizes; (void)n_in; (void)out_size; (void)ws_size;
    const float* x  = (const float*)d_in[0];
    const float* Wq = (const float*)d_in[1];
    const float* bq = (const float*)d_in[2];
    const float* Wk = (const float*)d_in[3];
    const float* bk = (const float*)d_in[4];
    const float* Wl = (const float*)d_in[5];
    const float* bl = (const float*)d_in[6];
    float* out = (float*)d_out;
    char* base = (char*)d_ws;

    short* Qt    = (short*)(base);
    short* Kt    = (short*)(base + 0x100000);
    short* Yc    = (short*)(base + 0x200000);
    float* mrow  = (float*)(base + 0x500000);
    short* Opart = (short*)(base + 0x510000);

    hipLaunchKernelGGL(k_proj, dim3(1024), dim3(256), 0, stream,
                       x, Wq, bq, Wk, bk, Wl, Qt, Kt, Yc);
    hipLaunchKernelGGL(k_pass1m, dim3(256), dim3(256), 0, stream, Qt, Kt, mrow);
    hipLaunchKernelGGL(k_pass2, dim3(1024), dim3(256), 0, stream,
                       Qt, Kt, Yc, mrow, Opart);
    hipLaunchKernelGGL(k_merge, dim3(1024), dim3(256), 0, stream, Opart, x, bl, out);
}

// Round 3
// 62.313 us; speedup vs baseline: 1.1126x; 1.1126x over previous
//
#include <hip/hip_runtime.h>
#include <hip/hip_bf16.h>

// SelfAttentionModule: B=4, C=64, CQ=32, HW=4096, fp32 in/out.
// out[c,j] = sum_i y[c,i]*exp2(qs_i.k_j - m_i) + bl[c] + x[c,j]
//   qs = LOG2E*(Wq x + bq), k = Wk x + bk, y = Wl x, m_i = log2(sum_j exp2(qs_i.k_j))
// R18 = R15 with pass1m j-split (occupancy-preserving traffic cut):
//   pass1m block = 64 i x 1024 j, grid 1024 (4 blocks/CU kept). Each K-tile load
//   feeds 4 MFMAs (4 i-tiles in regs). Kt L2 traffic 256MB -> 64MB. Blocks write
//   partial sums Spart[4][B*HW]; pass2 prologue combines -log2f(sum of 4) into MtA.
// pass2/proj/merge otherwise R15-verbatim.

#define HW 4096
#define BN 4
#define CD 64
#define ISPL 8
#define LOG2E 1.44269504f

typedef short bf16x8 __attribute__((ext_vector_type(8)));
typedef float f32x4 __attribute__((ext_vector_type(4)));

static __device__ inline unsigned bfbits(float f) {
    union { float f; unsigned u; } v{f};
    return (v.u + 0x8000u) >> 16;
}
static __device__ inline float b2f(short s) {
    unsigned u = ((unsigned)(unsigned short)s) << 16;
    float f; __builtin_memcpy(&f, &u, 4); return f;
}
static __device__ inline int cvtpk(float lo, float hi) {
    __hip_bfloat162 h = __float22bfloat162_rn(make_float2(lo, hi));
    int r; __builtin_memcpy(&r, &h, 4); return r;
}
static __device__ inline void gl16(const void* g, void* l) {
    __builtin_amdgcn_global_load_lds(
        (const __attribute__((address_space(1))) unsigned int*)g,
        (__attribute__((address_space(3))) unsigned int*)l, 16, 0, 0);
}

// ws (bytes): Qt[B*HW][32]bf16 @0 (1MB) | Kt @0x100000 (1MB) | Yc[B][64][HW]bf16 @0x200000 (2MB)
//  Spart[4][B*HW]f32 @0x500000 (256KB) | Opart[8][B][64][HW]bf16 @0x540000 (16.8MB)

// ---------------- proj: q,k,y projections via MFMA (R7 verbatim) ----------------

__global__ __launch_bounds__(256, 4) void k_proj(
    const float* __restrict__ x, const float* __restrict__ Wq, const float* __restrict__ bq,
    const float* __restrict__ Wk, const float* __restrict__ bk, const float* __restrict__ Wl,
    short* __restrict__ Qt, short* __restrict__ Kt, short* __restrict__ Yc)
{
    __shared__ __align__(16) char sm[18944];
    short* WcL   = (short*)sm;            // [128 rows][64] bf16, slot-swizzled (16KB)
    short* xT    = (short*)(sm + 16384);  // [16 px][64 c] bf16, slot-swizzled (2KB)
    float* biasL = (float*)(sm + 18432);  // [128] f32

    int t = threadIdx.x;
    int wv = t >> 6, l = t & 63, g = l >> 4, n = l & 15;

    {   // pack weights into LDS (redundant per block; L2-hot)
        int row = t >> 1, half = t & 1;
        const float* src; float scale = 1.f;
        if (row < 32)      { src = Wq + row * CD; scale = LOG2E; }
        else if (row < 64) { src = Wk + (row - 32) * CD; }
        else               { src = Wl + (row - 64) * CD; }
        int pk[16];
#pragma unroll
        for (int e = 0; e < 16; ++e)
            pk[e] = cvtpk(src[half * 32 + 2 * e] * scale, src[half * 32 + 2 * e + 1] * scale);
#pragma unroll
        for (int q = 0; q < 4; ++q)
            *(int4*)(WcL + row * 64 + ((((half << 2) + q) ^ (row & 7)) << 3)) =
                make_int4(pk[4 * q], pk[4 * q + 1], pk[4 * q + 2], pk[4 * q + 3]);
        if (half == 0)
            biasL[row] = (row < 32) ? LOG2E * bq[row] : (row < 64) ? bk[row - 32] : 0.f;
    }
    int pix0 = blockIdx.x << 4;           // 16 px per block over B*HW
    {
        int c = t >> 2, q = t & 3;
        int b = pix0 >> 12, pxb = pix0 & (HW - 1);
        float4 v = *(const float4*)(x + ((size_t)b << 18) + ((size_t)c << 12) + pxb + q * 4);
        float vv[4] = {v.x, v.y, v.z, v.w};
#pragma unroll
        for (int e = 0; e < 4; ++e) {
            int px = q * 4 + e;
            xT[px * 64 + (((c >> 3) ^ (px & 7)) << 3) + (c & 7)] = (short)bfbits(vv[e]);
        }
    }
    __syncthreads();

    bf16x8 B0 = *(const bf16x8*)(xT + n * 64 + ((g ^ (n & 7)) << 3));
    bf16x8 B1 = *(const bf16x8*)(xT + n * 64 + (((4 + g) ^ (n & 7)) << 3));
    int pg = pix0 + n;
#pragma unroll
    for (int mm = 0; mm < 2; ++mm) {
        int mt = wv * 2 + mm;
        bf16x8 A0 = *(const bf16x8*)(WcL + (mt * 16 + n) * 64 + ((g ^ (n & 7)) << 3));
        bf16x8 A1 = *(const bf16x8*)(WcL + (mt * 16 + n) * 64 + (((4 + g) ^ (n & 7)) << 3));
        f32x4 d = {0.f, 0.f, 0.f, 0.f};
        d = __builtin_amdgcn_mfma_f32_16x16x32_bf16(A0, B0, d, 0, 0, 0);
        d = __builtin_amdgcn_mfma_f32_16x16x32_bf16(A1, B1, d, 0, 0, 0);
        d += *(const f32x4*)(biasL + mt * 16 + g * 4);
        if (mt < 4) {
            short* dst = (mt < 2 ? Qt : Kt) + ((size_t)pg << 5) + ((mt & 1) << 4) + (g << 2);
            *(int2*)dst = make_int2(cvtpk(d[0], d[1]), cvtpk(d[2], d[3]));
        } else {
            int ch2 = (mt - 4) * 16 + g * 4;
            int bb = pg >> 12, ii = pg & (HW - 1);
#pragma unroll
            for (int r = 0; r < 4; ++r)
                Yc[(((size_t)(bb * CD + ch2 + r)) << 12) + ii] = (short)bfbits(d[r]);
        }
    }
}

// ---- pass1m (R18): partial S_i over a j-quarter; 64 i x 1024 j per block ----
// grid 1024 = 64 i-tiles x 4 jq x 4 b (b in low bits -> XCD-batch locality; each
// XCD touches one b and two jq -> 128KB of Kt, L2-resident). Each wave owns a
// 256-j strip; all 4 Q i-tiles in regs so one K load feeds 4 MFMAs.

__global__ __launch_bounds__(256, 4) void k_pass1m(
    const short* __restrict__ Qt, const short* __restrict__ Kt, float* __restrict__ Spart)
{
    __shared__ float red[256];            // [4 waves][64 i]
    int t = threadIdx.x;
    int wv = t >> 6, l = t & 63, g = l >> 4, n = l & 15;
    int ch = blockIdx.x;                  // 1024 = 64 it x 4 jq x 4 b
    int b = ch & 3, jq = (ch >> 2) & 3, i0 = (ch >> 4) << 6;
    size_t bHW = (size_t)b << 12;

    bf16x8 aq[4];                         // 4 Q i-tiles
#pragma unroll
    for (int it = 0; it < 4; ++it)
        aq[it] = *(const bf16x8*)(Qt + ((bHW + i0 + it * 16 + n) << 5) + (g << 3));

    f32x4 ls[4];
#pragma unroll
    for (int it = 0; it < 4; ++it) ls[it] = (f32x4){0.f, 0.f, 0.f, 0.f};

    const short* kbase = Kt + ((bHW + jq * 1024 + wv * 256 + n) << 5) + (g << 3);
#pragma unroll 4
    for (int jt = 0; jt < 16; ++jt) {     // wave's 256 j in 16-j tiles
        bf16x8 bkv = *(const bf16x8*)(kbase + jt * 512);
#pragma unroll
        for (int it = 0; it < 4; ++it) {
            f32x4 z = {0.f, 0.f, 0.f, 0.f};
            f32x4 s = __builtin_amdgcn_mfma_f32_16x16x32_bf16(aq[it], bkv, z, 0, 0, 0);
            ls[it][0] += exp2f(s[0]); ls[it][1] += exp2f(s[1]);
            ls[it][2] += exp2f(s[2]); ls[it][3] += exp2f(s[3]);
        }
    }
    // sum over the 16 j-columns of each MFMA tile (lane bits 0-3)
#pragma unroll
    for (int msk = 1; msk < 16; msk <<= 1)
#pragma unroll
        for (int it = 0; it < 4; ++it) {
            ls[it][0] += __shfl_xor(ls[it][0], msk, 64);
            ls[it][1] += __shfl_xor(ls[it][1], msk, 64);
            ls[it][2] += __shfl_xor(ls[it][2], msk, 64);
            ls[it][3] += __shfl_xor(ls[it][3], msk, 64);
        }
    if (n == 0)
#pragma unroll
        for (int it = 0; it < 4; ++it)
#pragma unroll
            for (int r = 0; r < 4; ++r)
                red[wv * 64 + it * 16 + g * 4 + r] = ls[it][r];
    __syncthreads();
    if (t < 64) {
        float s = red[t] + red[64 + t] + red[128 + t] + red[192 + t];
        Spart[(size_t)jq * 16384 + bHW + i0 + t] = s;   // partial over this j-quarter
    }
}

// --- pass2: R15 pipeline; prologue combines 4 S-partials -> -log2 -> MtA ---

__global__ __launch_bounds__(256, 4) void k_pass2(
    const short* __restrict__ Qt, const short* __restrict__ Kt,
    const short* __restrict__ Yc, const float* __restrict__ Spart,
    short* __restrict__ Opart)
{
    __shared__ __align__(16) char smem[36864];
    short* QtL = (short*)smem;              // 2 x [64 i][32 k]  (8KB)
    short* W2L = (short*)(smem + 8192);     // 2 x [64 c][64 i] swizzled (16KB)
    short* Pb  = (short*)(smem + 24576);    // 4 waves x [32 j][40] pitch-80B (10KB)
    float* MtA = (float*)(smem + 34816);    // full 512-i (-m) slice (2KB)

    int t = threadIdx.x;
    int wv = t >> 6, l = t & 63, g = l >> 4, n = l & 15;
    int ch = blockIdx.x;                    // 1024 = 4 b x 8 isp x 32 jt
    int b = ch >> 8, isp = (ch >> 5) & 7, jt = ch & 31;
    int j0 = jt * 128 + wv * 32;
    size_t bHW = (size_t)b << 12;
    short* Pw = Pb + wv * 1280;

    bf16x8 bk0 = *(const bf16x8*)(Kt + ((bHW + j0 + n) << 5) + (g << 3));
    bf16x8 bk1 = *(const bf16x8*)(Kt + ((bHW + j0 + 16 + n) << 5) + (g << 3));

    f32x4 oacc[2][4];
#pragma unroll
    for (int a = 0; a < 2; ++a)
#pragma unroll
        for (int m = 0; m < 4; ++m) oacc[a][m] = (f32x4){0.f, 0.f, 0.f, 0.f};

    int swz = ((t & 7) ^ ((t >> 3) & 7)) << 4;
    const char* qsrc = (const char*)Qt + ((bHW + (size_t)isp * 512) << 6) + t * 16;
    const char* wsrc = (const char*)Yc + (((size_t)(b * CD + (t >> 3)) << 12) + isp * 512) * 2 + swz;
    char* qd0 = (char*)QtL + t * 16;  char* qd1 = qd0 + 4096;
    char* wd0 = (char*)W2L + t * 16;  char* wd1 = wd0 + 8192;

    // prologue: stage buf0; combine the 4 S-partials into -m (MtA); full drain once.
    gl16(qsrc, qd0);
    gl16(wsrc, wd0);
    gl16(wsrc + (32ull << 13), wd0 + 4096);
    if (t < 128) {   // waves 0-1 (wave-uniform): 128 x 4 i = this block's 512 i
        const float* sp = Spart + bHW + (size_t)isp * 512 + t * 4;
        float4 a0 = *(const float4*)(sp);
        float4 a1 = *(const float4*)(sp + 16384);
        float4 a2 = *(const float4*)(sp + 32768);
        float4 a3 = *(const float4*)(sp + 49152);
        float4 mm;
        mm.x = -log2f(a0.x + a1.x + a2.x + a3.x);
        mm.y = -log2f(a0.y + a1.y + a2.y + a3.y);
        mm.z = -log2f(a0.z + a1.z + a2.z + a3.z);
        mm.w = -log2f(a0.w + a1.w + a2.w + a3.w);
        *(float4*)(MtA + t * 4) = mm;
    }
    asm volatile("s_waitcnt vmcnt(0) lgkmcnt(0)" ::: "memory");
    __builtin_amdgcn_s_barrier();
    __builtin_amdgcn_sched_barrier(0);

    const int NT = 8;                       // 512 i / 64
    for (int st = 0; st < NT; ++st) {
        int cur = st & 1;
        if (st > 0) {
            // single barrier per step: proves all waves finished reading
            // buf[cur^1] (step st-1's compute) before DMA overwrites it below.
            __builtin_amdgcn_s_barrier();
            __builtin_amdgcn_sched_barrier(0);
        }
        if (st + 1 < NT) {
            gl16(qsrc + (size_t)(st + 1) * 4096, cur ? qd0 : qd1);
            gl16(wsrc + (size_t)(st + 1) * 128, cur ? wd0 : wd1);
            gl16(wsrc + (size_t)(st + 1) * 128 + (32ull << 13), (cur ? wd0 : wd1) + 4096);
            // wait for THIS step's 3 loads (issued at st-1); st+1's 3 stay in flight
            asm volatile("s_waitcnt vmcnt(3)" ::: "memory");
        } else {
            asm volatile("s_waitcnt vmcnt(0)" ::: "memory");
        }
        __builtin_amdgcn_sched_barrier(0);  // no ds_read hoists above (rule #18)

        const short* qL = QtL + cur * 2048;
        const char* wL = (const char*)W2L + cur * 8192;
        const float* mL = MtA + st * 64;
#pragma unroll
        for (int ks = 0; ks < 2; ++ks) {
            bf16x8 aq0 = *(const bf16x8*)(qL + (ks * 32 + n) * 32 + g * 8);
            bf16x8 aq1 = *(const bf16x8*)(qL + (ks * 32 + 16 + n) * 32 + g * 8);
            f32x4 cm0 = *(const f32x4*)(mL + ks * 32 + g * 4);
            f32x4 cm1 = *(const f32x4*)(mL + ks * 32 + 16 + g * 4);
            __builtin_amdgcn_s_setprio(1);
            f32x4 s00 = __builtin_amdgcn_mfma_f32_16x16x32_bf16(aq0, bk0, cm0, 0, 0, 0);
            f32x4 s01 = __builtin_amdgcn_mfma_f32_16x16x32_bf16(aq1, bk0, cm1, 0, 0, 0);
            f32x4 s10 = __builtin_amdgcn_mfma_f32_16x16x32_bf16(aq0, bk1, cm0, 0, 0, 0);
            f32x4 s11 = __builtin_amdgcn_mfma_f32_16x16x32_bf16(aq1, bk1, cm1, 0, 0, 0);
            __builtin_amdgcn_s_setprio(0);
            *(int2*)(Pw + n * 40 + 4 * g) =
                make_int2(cvtpk(exp2f(s00[0]), exp2f(s00[1])), cvtpk(exp2f(s00[2]), exp2f(s00[3])));
            *(int2*)(Pw + n * 40 + 16 + 4 * g) =
                make_int2(cvtpk(exp2f(s01[0]), exp2f(s01[1])), cvtpk(exp2f(s01[2]), exp2f(s01[3])));
            *(int2*)(Pw + (16 + n) * 40 + 4 * g) =
                make_int2(cvtpk(exp2f(s10[0]), exp2f(s10[1])), cvtpk(exp2f(s10[2]), exp2f(s10[3])));
            *(int2*)(Pw + (16 + n) * 40 + 16 + 4 * g) =
                make_int2(cvtpk(exp2f(s11[0]), exp2f(s11[1])), cvtpk(exp2f(s11[2]), exp2f(s11[3])));
            bf16x8 pb0 = *(const bf16x8*)(Pw + n * 40 + 8 * g);
            bf16x8 pb1 = *(const bf16x8*)(Pw + (16 + n) * 40 + 8 * g);
            __builtin_amdgcn_s_setprio(1);
#pragma unroll
            for (int mb = 0; mb < 4; ++mb) {
                bf16x8 aw = *(const bf16x8*)(wL + (mb * 16 + n) * 128 + ((((ks << 2) + g) ^ (n & 7)) << 4));
                oacc[0][mb] = __builtin_amdgcn_mfma_f32_16x16x32_bf16(aw, pb0, oacc[0][mb], 0, 0, 0);
                oacc[1][mb] = __builtin_amdgcn_mfma_f32_16x16x32_bf16(aw, pb1, oacc[1][mb], 0, 0, 0);
            }
            __builtin_amdgcn_s_setprio(0);
        }
        __builtin_amdgcn_sched_barrier(0);  // no ds_read sinks past next barrier
    }
    size_t obase = ((((size_t)isp * BN + b) * CD) << 12) + j0 + n;
#pragma unroll
    for (int j2 = 0; j2 < 2; ++j2)
#pragma unroll
        for (int mb = 0; mb < 4; ++mb)
#pragma unroll
            for (int r = 0; r < 4; ++r)
                Opart[obase + (((size_t)(mb * 16 + g * 4 + r)) << 12) + j2 * 16] =
                    (short)bfbits(oacc[j2][mb][r]);
}

// ---------------- merge (R15 verbatim): sum partials + bias + residual ----------------

__global__ __launch_bounds__(256, 4) void k_merge(
    const short* __restrict__ Opart, const float* __restrict__ x,
    const float* __restrict__ bl, float* __restrict__ out)
{
    int t = threadIdx.x;
    int e = (blockIdx.x * 256 + t) * 4;
    int c = (e >> 12) & 63;
    float4 r = *(const float4*)(x + e);
    float bc = bl[c];
    r.x += bc; r.y += bc; r.z += bc; r.w += bc;
#pragma unroll
    for (int p = 0; p < ISPL; ++p) {
        int2 o4 = *(const int2*)(Opart + ((size_t)p << 20) + e);
        r.x += b2f((short)(o4.x & 0xffff));
        r.y += b2f((short)(o4.x >> 16));
        r.z += b2f((short)(o4.y & 0xffff));
        r.w += b2f((short)(o4.y >> 16));
    }
    *(float4*)(out + e) = r;
}

extern "C" void kernel_launch(void* const* d_in, const int* in_sizes, int n_in,
                              void* d_out, int out_size, void* d_ws, size_t ws_size,
                              hipStream_t stream)
{
    (void)in_sizes; (void)n_in; (void)out_size; (void)ws_size;
    const float* x  = (const float*)d_in[0];
    const float* Wq = (const float*)d_in[1];
    const float* bq = (const float*)d_in[2];
    const float* Wk = (const float*)d_in[3];
    const float* bk = (const float*)d_in[4];
    const float* Wl = (const float*)d_in[5];
    const float* bl = (const float*)d_in[6];
    float* out = (float*)d_out;
    char* base = (char*)d_ws;

    short* Qt    = (short*)(base);
    short* Kt    = (short*)(base + 0x100000);
    short* Yc    = (short*)(base + 0x200000);
    float* Spart = (float*)(base + 0x500000);
    short* Opart = (short*)(base + 0x540000);

    hipLaunchKernelGGL(k_proj, dim3(1024), dim3(256), 0, stream,
                       x, Wq, bq, Wk, bk, Wl, Qt, Kt, Yc);
    hipLaunchKernelGGL(k_pass1m, dim3(1024), dim3(256), 0, stream, Qt, Kt, Spart);
    hipLaunchKernelGGL(k_pass2, dim3(1024), dim3(256), 0, stream,
                       Qt, Kt, Yc, Spart, Opart);
    hipLaunchKernelGGL(k_merge, dim3(1024), dim3(256), 0, stream, Opart, x, bl, out);
}

// Round 4
// 62.183 us; speedup vs baseline: 1.1149x; 1.0021x over previous
//
#include <hip/hip_runtime.h>
#include <hip/hip_bf16.h>

// SelfAttentionModule: B=4, C=64, CQ=32, HW=4096, fp32 in/out.
// out[c,j] = sum_i y[c,i]*exp2(qs_i.k_j - m_i) + bl[c] + x[c,j]
//   qs = LOG2E*(Wq x + bq), k = Wk x + bk, y = Wl x, m_i = log2(sum_j exp2(qs_i.k_j))
// R19 = R18 with Opart layout change (bit-identical values):
//   Opart stored as dwords; dword n of each 32-j group packs (j_base+n | j_base+n+16<<16)
//   = exactly (oacc[0],oacc[1]) per (mb,r). pass2 epilogue: 32 short-stores -> 16
//   dword-stores. merge: 8 elems/thread, int4 (16B) Opart loads, grid 512.
// proj/pass1m/pass2-loop R18-verbatim.

#define HW 4096
#define BN 4
#define CD 64
#define ISPL 8
#define LOG2E 1.44269504f

typedef short bf16x8 __attribute__((ext_vector_type(8)));
typedef float f32x4 __attribute__((ext_vector_type(4)));

static __device__ inline unsigned bfbits(float f) {
    union { float f; unsigned u; } v{f};
    return (v.u + 0x8000u) >> 16;
}
static __device__ inline float b2f(short s) {
    unsigned u = ((unsigned)(unsigned short)s) << 16;
    float f; __builtin_memcpy(&f, &u, 4); return f;
}
static __device__ inline int cvtpk(float lo, float hi) {
    __hip_bfloat162 h = __float22bfloat162_rn(make_float2(lo, hi));
    int r; __builtin_memcpy(&r, &h, 4); return r;
}
static __device__ inline void gl16(const void* g, void* l) {
    __builtin_amdgcn_global_load_lds(
        (const __attribute__((address_space(1))) unsigned int*)g,
        (__attribute__((address_space(3))) unsigned int*)l, 16, 0, 0);
}

// ws (bytes): Qt[B*HW][32]bf16 @0 (1MB) | Kt @0x100000 (1MB) | Yc[B][64][HW]bf16 @0x200000 (2MB)
//  Spart[4][B*HW]f32 @0x500000 (256KB) | Opart[8][B][64][2048]dw @0x540000 (16.8MB)

// ---------------- proj: q,k,y projections via MFMA (R7 verbatim) ----------------

__global__ __launch_bounds__(256, 4) void k_proj(
    const float* __restrict__ x, const float* __restrict__ Wq, const float* __restrict__ bq,
    const float* __restrict__ Wk, const float* __restrict__ bk, const float* __restrict__ Wl,
    short* __restrict__ Qt, short* __restrict__ Kt, short* __restrict__ Yc)
{
    __shared__ __align__(16) char sm[18944];
    short* WcL   = (short*)sm;            // [128 rows][64] bf16, slot-swizzled (16KB)
    short* xT    = (short*)(sm + 16384);  // [16 px][64 c] bf16, slot-swizzled (2KB)
    float* biasL = (float*)(sm + 18432);  // [128] f32

    int t = threadIdx.x;
    int wv = t >> 6, l = t & 63, g = l >> 4, n = l & 15;

    {   // pack weights into LDS (redundant per block; L2-hot)
        int row = t >> 1, half = t & 1;
        const float* src; float scale = 1.f;
        if (row < 32)      { src = Wq + row * CD; scale = LOG2E; }
        else if (row < 64) { src = Wk + (row - 32) * CD; }
        else               { src = Wl + (row - 64) * CD; }
        int pk[16];
#pragma unroll
        for (int e = 0; e < 16; ++e)
            pk[e] = cvtpk(src[half * 32 + 2 * e] * scale, src[half * 32 + 2 * e + 1] * scale);
#pragma unroll
        for (int q = 0; q < 4; ++q)
            *(int4*)(WcL + row * 64 + ((((half << 2) + q) ^ (row & 7)) << 3)) =
                make_int4(pk[4 * q], pk[4 * q + 1], pk[4 * q + 2], pk[4 * q + 3]);
        if (half == 0)
            biasL[row] = (row < 32) ? LOG2E * bq[row] : (row < 64) ? bk[row - 32] : 0.f;
    }
    int pix0 = blockIdx.x << 4;           // 16 px per block over B*HW
    {
        int c = t >> 2, q = t & 3;
        int b = pix0 >> 12, pxb = pix0 & (HW - 1);
        float4 v = *(const float4*)(x + ((size_t)b << 18) + ((size_t)c << 12) + pxb + q * 4);
        float vv[4] = {v.x, v.y, v.z, v.w};
#pragma unroll
        for (int e = 0; e < 4; ++e) {
            int px = q * 4 + e;
            xT[px * 64 + (((c >> 3) ^ (px & 7)) << 3) + (c & 7)] = (short)bfbits(vv[e]);
        }
    }
    __syncthreads();

    bf16x8 B0 = *(const bf16x8*)(xT + n * 64 + ((g ^ (n & 7)) << 3));
    bf16x8 B1 = *(const bf16x8*)(xT + n * 64 + (((4 + g) ^ (n & 7)) << 3));
    int pg = pix0 + n;
#pragma unroll
    for (int mm = 0; mm < 2; ++mm) {
        int mt = wv * 2 + mm;
        bf16x8 A0 = *(const bf16x8*)(WcL + (mt * 16 + n) * 64 + ((g ^ (n & 7)) << 3));
        bf16x8 A1 = *(const bf16x8*)(WcL + (mt * 16 + n) * 64 + (((4 + g) ^ (n & 7)) << 3));
        f32x4 d = {0.f, 0.f, 0.f, 0.f};
        d = __builtin_amdgcn_mfma_f32_16x16x32_bf16(A0, B0, d, 0, 0, 0);
        d = __builtin_amdgcn_mfma_f32_16x16x32_bf16(A1, B1, d, 0, 0, 0);
        d += *(const f32x4*)(biasL + mt * 16 + g * 4);
        if (mt < 4) {
            short* dst = (mt < 2 ? Qt : Kt) + ((size_t)pg << 5) + ((mt & 1) << 4) + (g << 2);
            *(int2*)dst = make_int2(cvtpk(d[0], d[1]), cvtpk(d[2], d[3]));
        } else {
            int ch2 = (mt - 4) * 16 + g * 4;
            int bb = pg >> 12, ii = pg & (HW - 1);
#pragma unroll
            for (int r = 0; r < 4; ++r)
                Yc[(((size_t)(bb * CD + ch2 + r)) << 12) + ii] = (short)bfbits(d[r]);
        }
    }
}

// ---- pass1m (R18 verbatim): partial S_i over a j-quarter; 64 i x 1024 j per block ----

__global__ __launch_bounds__(256, 4) void k_pass1m(
    const short* __restrict__ Qt, const short* __restrict__ Kt, float* __restrict__ Spart)
{
    __shared__ float red[256];            // [4 waves][64 i]
    int t = threadIdx.x;
    int wv = t >> 6, l = t & 63, g = l >> 4, n = l & 15;
    int ch = blockIdx.x;                  // 1024 = 64 it x 4 jq x 4 b
    int b = ch & 3, jq = (ch >> 2) & 3, i0 = (ch >> 4) << 6;
    size_t bHW = (size_t)b << 12;

    bf16x8 aq[4];                         // 4 Q i-tiles
#pragma unroll
    for (int it = 0; it < 4; ++it)
        aq[it] = *(const bf16x8*)(Qt + ((bHW + i0 + it * 16 + n) << 5) + (g << 3));

    f32x4 ls[4];
#pragma unroll
    for (int it = 0; it < 4; ++it) ls[it] = (f32x4){0.f, 0.f, 0.f, 0.f};

    const short* kbase = Kt + ((bHW + jq * 1024 + wv * 256 + n) << 5) + (g << 3);
#pragma unroll 4
    for (int jt = 0; jt < 16; ++jt) {     // wave's 256 j in 16-j tiles
        bf16x8 bkv = *(const bf16x8*)(kbase + jt * 512);
#pragma unroll
        for (int it = 0; it < 4; ++it) {
            f32x4 z = {0.f, 0.f, 0.f, 0.f};
            f32x4 s = __builtin_amdgcn_mfma_f32_16x16x32_bf16(aq[it], bkv, z, 0, 0, 0);
            ls[it][0] += exp2f(s[0]); ls[it][1] += exp2f(s[1]);
            ls[it][2] += exp2f(s[2]); ls[it][3] += exp2f(s[3]);
        }
    }
    // sum over the 16 j-columns of each MFMA tile (lane bits 0-3)
#pragma unroll
    for (int msk = 1; msk < 16; msk <<= 1)
#pragma unroll
        for (int it = 0; it < 4; ++it) {
            ls[it][0] += __shfl_xor(ls[it][0], msk, 64);
            ls[it][1] += __shfl_xor(ls[it][1], msk, 64);
            ls[it][2] += __shfl_xor(ls[it][2], msk, 64);
            ls[it][3] += __shfl_xor(ls[it][3], msk, 64);
        }
    if (n == 0)
#pragma unroll
        for (int it = 0; it < 4; ++it)
#pragma unroll
            for (int r = 0; r < 4; ++r)
                red[wv * 64 + it * 16 + g * 4 + r] = ls[it][r];
    __syncthreads();
    if (t < 64) {
        float s = red[t] + red[64 + t] + red[128 + t] + red[192 + t];
        Spart[(size_t)jq * 16384 + bHW + i0 + t] = s;   // partial over this j-quarter
    }
}

// --- pass2: R18 pipeline; epilogue packs (j, j+16) into one dword per (mb,r) ---

__global__ __launch_bounds__(256, 4) void k_pass2(
    const short* __restrict__ Qt, const short* __restrict__ Kt,
    const short* __restrict__ Yc, const float* __restrict__ Spart,
    int* __restrict__ Opart)
{
    __shared__ __align__(16) char smem[36864];
    short* QtL = (short*)smem;              // 2 x [64 i][32 k]  (8KB)
    short* W2L = (short*)(smem + 8192);     // 2 x [64 c][64 i] swizzled (16KB)
    short* Pb  = (short*)(smem + 24576);    // 4 waves x [32 j][40] pitch-80B (10KB)
    float* MtA = (float*)(smem + 34816);    // full 512-i (-m) slice (2KB)

    int t = threadIdx.x;
    int wv = t >> 6, l = t & 63, g = l >> 4, n = l & 15;
    int ch = blockIdx.x;                    // 1024 = 4 b x 8 isp x 32 jt
    int b = ch >> 8, isp = (ch >> 5) & 7, jt = ch & 31;
    int j0 = jt * 128 + wv * 32;
    size_t bHW = (size_t)b << 12;
    short* Pw = Pb + wv * 1280;

    bf16x8 bk0 = *(const bf16x8*)(Kt + ((bHW + j0 + n) << 5) + (g << 3));
    bf16x8 bk1 = *(const bf16x8*)(Kt + ((bHW + j0 + 16 + n) << 5) + (g << 3));

    f32x4 oacc[2][4];
#pragma unroll
    for (int a = 0; a < 2; ++a)
#pragma unroll
        for (int m = 0; m < 4; ++m) oacc[a][m] = (f32x4){0.f, 0.f, 0.f, 0.f};

    int swz = ((t & 7) ^ ((t >> 3) & 7)) << 4;
    const char* qsrc = (const char*)Qt + ((bHW + (size_t)isp * 512) << 6) + t * 16;
    const char* wsrc = (const char*)Yc + (((size_t)(b * CD + (t >> 3)) << 12) + isp * 512) * 2 + swz;
    char* qd0 = (char*)QtL + t * 16;  char* qd1 = qd0 + 4096;
    char* wd0 = (char*)W2L + t * 16;  char* wd1 = wd0 + 8192;

    // prologue: stage buf0; combine the 4 S-partials into -m (MtA); full drain once.
    gl16(qsrc, qd0);
    gl16(wsrc, wd0);
    gl16(wsrc + (32ull << 13), wd0 + 4096);
    if (t < 128) {   // waves 0-1 (wave-uniform): 128 x 4 i = this block's 512 i
        const float* sp = Spart + bHW + (size_t)isp * 512 + t * 4;
        float4 a0 = *(const float4*)(sp);
        float4 a1 = *(const float4*)(sp + 16384);
        float4 a2 = *(const float4*)(sp + 32768);
        float4 a3 = *(const float4*)(sp + 49152);
        float4 mm;
        mm.x = -log2f(a0.x + a1.x + a2.x + a3.x);
        mm.y = -log2f(a0.y + a1.y + a2.y + a3.y);
        mm.z = -log2f(a0.z + a1.z + a2.z + a3.z);
        mm.w = -log2f(a0.w + a1.w + a2.w + a3.w);
        *(float4*)(MtA + t * 4) = mm;
    }
    asm volatile("s_waitcnt vmcnt(0) lgkmcnt(0)" ::: "memory");
    __builtin_amdgcn_s_barrier();
    __builtin_amdgcn_sched_barrier(0);

    const int NT = 8;                       // 512 i / 64
    for (int st = 0; st < NT; ++st) {
        int cur = st & 1;
        if (st > 0) {
            // single barrier per step: proves all waves finished reading
            // buf[cur^1] (step st-1's compute) before DMA overwrites it below.
            __builtin_amdgcn_s_barrier();
            __builtin_amdgcn_sched_barrier(0);
        }
        if (st + 1 < NT) {
            gl16(qsrc + (size_t)(st + 1) * 4096, cur ? qd0 : qd1);
            gl16(wsrc + (size_t)(st + 1) * 128, cur ? wd0 : wd1);
            gl16(wsrc + (size_t)(st + 1) * 128 + (32ull << 13), (cur ? wd0 : wd1) + 4096);
            // wait for THIS step's 3 loads (issued at st-1); st+1's 3 stay in flight
            asm volatile("s_waitcnt vmcnt(3)" ::: "memory");
        } else {
            asm volatile("s_waitcnt vmcnt(0)" ::: "memory");
        }
        __builtin_amdgcn_sched_barrier(0);  // no ds_read hoists above (rule #18)

        const short* qL = QtL + cur * 2048;
        const char* wL = (const char*)W2L + cur * 8192;
        const float* mL = MtA + st * 64;
#pragma unroll
        for (int ks = 0; ks < 2; ++ks) {
            bf16x8 aq0 = *(const bf16x8*)(qL + (ks * 32 + n) * 32 + g * 8);
            bf16x8 aq1 = *(const bf16x8*)(qL + (ks * 32 + 16 + n) * 32 + g * 8);
            f32x4 cm0 = *(const f32x4*)(mL + ks * 32 + g * 4);
            f32x4 cm1 = *(const f32x4*)(mL + ks * 32 + 16 + g * 4);
            __builtin_amdgcn_s_setprio(1);
            f32x4 s00 = __builtin_amdgcn_mfma_f32_16x16x32_bf16(aq0, bk0, cm0, 0, 0, 0);
            f32x4 s01 = __builtin_amdgcn_mfma_f32_16x16x32_bf16(aq1, bk0, cm1, 0, 0, 0);
            f32x4 s10 = __builtin_amdgcn_mfma_f32_16x16x32_bf16(aq0, bk1, cm0, 0, 0, 0);
            f32x4 s11 = __builtin_amdgcn_mfma_f32_16x16x32_bf16(aq1, bk1, cm1, 0, 0, 0);
            __builtin_amdgcn_s_setprio(0);
            *(int2*)(Pw + n * 40 + 4 * g) =
                make_int2(cvtpk(exp2f(s00[0]), exp2f(s00[1])), cvtpk(exp2f(s00[2]), exp2f(s00[3])));
            *(int2*)(Pw + n * 40 + 16 + 4 * g) =
                make_int2(cvtpk(exp2f(s01[0]), exp2f(s01[1])), cvtpk(exp2f(s01[2]), exp2f(s01[3])));
            *(int2*)(Pw + (16 + n) * 40 + 4 * g) =
                make_int2(cvtpk(exp2f(s10[0]), exp2f(s10[1])), cvtpk(exp2f(s10[2]), exp2f(s10[3])));
            *(int2*)(Pw + (16 + n) * 40 + 16 + 4 * g) =
                make_int2(cvtpk(exp2f(s11[0]), exp2f(s11[1])), cvtpk(exp2f(s11[2]), exp2f(s11[3])));
            bf16x8 pb0 = *(const bf16x8*)(Pw + n * 40 + 8 * g);
            bf16x8 pb1 = *(const bf16x8*)(Pw + (16 + n) * 40 + 8 * g);
            __builtin_amdgcn_s_setprio(1);
#pragma unroll
            for (int mb = 0; mb < 4; ++mb) {
                bf16x8 aw = *(const bf16x8*)(wL + (mb * 16 + n) * 128 + ((((ks << 2) + g) ^ (n & 7)) << 4));
                oacc[0][mb] = __builtin_amdgcn_mfma_f32_16x16x32_bf16(aw, pb0, oacc[0][mb], 0, 0, 0);
                oacc[1][mb] = __builtin_amdgcn_mfma_f32_16x16x32_bf16(aw, pb1, oacc[1][mb], 0, 0, 0);
            }
            __builtin_amdgcn_s_setprio(0);
        }
        __builtin_amdgcn_sched_barrier(0);  // no ds_read sinks past next barrier
    }
    // epilogue: dword n of each 32-j group = (j0+n) | (j0+n+16)<<16
    size_t obase = ((size_t)(isp * BN + b)) << 17;   // row block base in dwords
    int doff = jt * 64 + wv * 16 + n;
#pragma unroll
    for (int mb = 0; mb < 4; ++mb)
#pragma unroll
        for (int r = 0; r < 4; ++r) {
            int c = mb * 16 + g * 4 + r;
            Opart[obase + ((size_t)c << 11) + doff] =
                (int)bfbits(oacc[0][mb][r]) | ((int)bfbits(oacc[1][mb][r]) << 16);
        }
}

// ---- merge (R19): 8 elems/thread, int4 Opart loads; un-interleave (j, j+16) ----

__global__ __launch_bounds__(256, 4) void k_merge(
    const int* __restrict__ Opart, const float* __restrict__ x,
    const float* __restrict__ bl, float* __restrict__ out)
{
    int T = blockIdx.x * 256 + threadIdx.x;  // [0, 131072)
    int row = T >> 9;                        // b*64 + c  (256 rows of 4096 j)
    int u = T & 511;
    int g32 = u >> 2, sub = u & 3;           // 128 j-groups/row, 4 threads/group
    int jlo = g32 * 32 + sub * 4;
    size_t rbase = (size_t)row << 12;
    float4 rl = *(const float4*)(x + rbase + jlo);
    float4 rh = *(const float4*)(x + rbase + jlo + 16);
    float bc = bl[row & 63];
    rl.x += bc; rl.y += bc; rl.z += bc; rl.w += bc;
    rh.x += bc; rh.y += bc; rh.z += bc; rh.w += bc;
    size_t dbase = ((size_t)row << 11) + g32 * 16 + sub * 4;
#pragma unroll
    for (int p = 0; p < ISPL; ++p) {
        int4 d = *(const int4*)(Opart + ((size_t)p << 19) + dbase);
        rl.x += b2f((short)(d.x & 0xffff)); rh.x += b2f((short)(d.x >> 16));
        rl.y += b2f((short)(d.y & 0xffff)); rh.y += b2f((short)(d.y >> 16));
        rl.z += b2f((short)(d.z & 0xffff)); rh.z += b2f((short)(d.z >> 16));
        rl.w += b2f((short)(d.w & 0xffff)); rh.w += b2f((short)(d.w >> 16));
    }
    *(float4*)(out + rbase + jlo) = rl;
    *(float4*)(out + rbase + jlo + 16) = rh;
}

extern "C" void kernel_launch(void* const* d_in, const int* in_sizes, int n_in,
                              void* d_out, int out_size, void* d_ws, size_t ws_size,
                              hipStream_t stream)
{
    (void)in_sizes; (void)n_in; (void)out_size; (void)ws_size;
    const float* x  = (const float*)d_in[0];
    const float* Wq = (const float*)d_in[1];
    const float* bq = (const float*)d_in[2];
    const float* Wk = (const float*)d_in[3];
    const float* bk = (const float*)d_in[4];
    const float* Wl = (const float*)d_in[5];
    const float* bl = (const float*)d_in[6];
    float* out = (float*)d_out;
    char* base = (char*)d_ws;

    short* Qt    = (short*)(base);
    short* Kt    = (short*)(base + 0x100000);
    short* Yc    = (short*)(base + 0x200000);
    float* Spart = (float*)(base + 0x500000);
    int*   Opart = (int*)(base + 0x540000);

    hipLaunchKernelGGL(k_proj, dim3(1024), dim3(256), 0, stream,
                       x, Wq, bq, Wk, bk, Wl, Qt, Kt, Yc);
    hipLaunchKernelGGL(k_pass1m, dim3(1024), dim3(256), 0, stream, Qt, Kt, Spart);
    hipLaunchKernelGGL(k_pass2, dim3(1024), dim3(256), 0, stream,
                       Qt, Kt, Yc, Spart, Opart);
    hipLaunchKernelGGL(k_merge, dim3(512), dim3(256), 0, stream, Opart, x, bl, out);
}